// Round 25
// baseline (103.806 us; speedup 1.0000x reference)
//
#include <hip/hip_runtime.h>
#include <hip/hip_bf16.h>

#define D_ 128
#define E_ 100
#define K_ 4
#define C_ 400
#define NCHUNK 128     // atom chunks in k_sums3 (x2 dim-halves = 256 blocks)
#define SCALE 65536.0f
#define INV_SCALE (1.0f / 65536.0f)

// ws layout (f32/i32 slots):
#define OFF_COUNTS 51200
#define OFF_LOSS   51600
#define OFF_PSUM   51712
#define PSUM_SZ    (256 * C_ * 64)
#define OFF_PCNT   (OFF_PSUM + PSUM_SZ)
#define WS_NEED_PART ((size_t)(OFF_PCNT + NCHUNK * C_) * 4)

typedef float f32x4 __attribute__((ext_vector_type(4)));

__device__ __forceinline__ void nt_store4(float4 v, float4* p) {
  __builtin_nontemporal_store(__builtin_bit_cast(f32x4, v), (f32x4*)p);
}

template <int CTRL>
__device__ __forceinline__ float dpp_add(float x) {
  int y = __builtin_amdgcn_update_dpp(0, __builtin_bit_cast(int, x),
                                      CTRL, 0xF, 0xF, true);
  return x + __builtin_bit_cast(float, y);
}

// Kernel 1: streaming argmin, 32 LANES PER ATOM (wave = 2 adjacent atoms).
// Lane owns one float4 (4 dims). Every h load / hq store instruction is ONE
// fully-contiguous 1KB block (2 rows); each cb row is one contiguous 512B
// instruction. ~3.5 mem instrs/atom vs ~9 in all prior variants. Reduce =
// 4 DPP steps + one shfl_xor(16). nt hq stores; 1-deep prefetch.
__global__ __launch_bounds__(256) void k_assign32(
    const float* __restrict__ h, const int* __restrict__ ei,
    const float* __restrict__ cb, float* __restrict__ hq,
    float* __restrict__ at, float* __restrict__ loss_acc, int N) {
  const int L = threadIdx.x & 31;                         // lane within atom
  const int gid = (blockIdx.x * 256 + threadIdx.x) >> 5;  // 32-lane group id
  const int ng = (gridDim.x * 256) >> 5;                  // group count
  const float4* h4 = (const float4*)h;
  const float4* cb4 = (const float4*)cb;
  float4* hq4 = (float4*)hq;
  float loss = 0.f;

  int a = gid;
  bool ok = a < N;
  const int as = ok ? a : 0;
  int e = ei[as];
  float4 hv = h4[(size_t)as * 32 + L];

  while (ok) {
    const int an = a + ng;
    const bool okn = an < N;
    const int ans = okn ? an : a;
    const int en = ei[ans];
    const float4 hvn = h4[(size_t)ans * 32 + L];

    // 4 codebook rows, each one contiguous 512B segment per 32-lane group
    const size_t cb0 = (size_t)e * 128 + L;
    const float4 c0 = cb4[cb0];
    const float4 c1 = cb4[cb0 + 32];
    const float4 c2 = cb4[cb0 + 64];
    const float4 c3 = cb4[cb0 + 96];

    float d0, d1, d2, d3;
#define DIST(cv, P) \
    d0 = hv.x - cv.x; d1 = hv.y - cv.y; d2 = hv.z - cv.z; d3 = hv.w - cv.w; \
    float P = (d0 * d0 + d1 * d1) + (d2 * d2 + d3 * d3);
    DIST(c0, p0) DIST(c1, p1) DIST(c2, p2) DIST(c3, p3)
#undef DIST

    // 32-lane reduce: 4 DPP steps (xor1,2,4,8) + one shfl_xor(16)
    p0 = dpp_add<0xB1>(p0); p1 = dpp_add<0xB1>(p1);
    p2 = dpp_add<0xB1>(p2); p3 = dpp_add<0xB1>(p3);
    p0 = dpp_add<0x4E>(p0); p1 = dpp_add<0x4E>(p1);
    p2 = dpp_add<0x4E>(p2); p3 = dpp_add<0x4E>(p3);
    p0 = dpp_add<0x141>(p0); p1 = dpp_add<0x141>(p1);
    p2 = dpp_add<0x141>(p2); p3 = dpp_add<0x141>(p3);
    p0 = dpp_add<0x140>(p0); p1 = dpp_add<0x140>(p1);
    p2 = dpp_add<0x140>(p2); p3 = dpp_add<0x140>(p3);
    p0 += __shfl_xor(p0, 16, 64);
    p1 += __shfl_xor(p1, 16, 64);
    p2 += __shfl_xor(p2, 16, 64);
    p3 += __shfl_xor(p3, 16, 64);

    int best = 0; float bp = p0;
    if (p1 < bp) { bp = p1; best = 1; }
    if (p2 < bp) { bp = p2; best = 2; }
    if (p3 < bp) { bp = p3; best = 3; }

    float4 q = c0;
    if (best == 1) q = c1;
    if (best == 2) q = c2;
    if (best == 3) q = c3;
    nt_store4(q, &hq4[(size_t)a * 32 + L]);
    if (L == 0) {
      at[a] = (float)(e * K_ + best);
      loss += bp;
    }

    a = an; ok = okn; e = en; hv = hvn;
  }

  // loss lives on lanes 0 and 32 of each wave
  loss += __shfl_xor(loss, 32, 64);
  __shared__ float wl[4];
  const int w = threadIdx.x >> 6;
  if ((threadIdx.x & 63) == 0) wl[w] = loss;
  __syncthreads();
  if (threadIdx.x == 0)
    atomicAdd(loss_acc, wl[0] + wl[1] + wl[2] + wl[3]);
}

// Kernel 2: streaming segment-sum + counts with NATIVE s32 LDS atomics.
__global__ __launch_bounds__(1024) void k_sums3(
    const float* __restrict__ h, const float* __restrict__ at,
    int* __restrict__ psumI, int* __restrict__ pcntI,
    float* __restrict__ sums, float* __restrict__ countsF,
    int dopart, int N) {
  const int half = blockIdx.x & 1;
  const int chunk = blockIdx.x >> 1;
  __shared__ int acc[C_ * 64];
  __shared__ int cnt[C_];
  for (int i = threadIdx.x; i < C_ * 64; i += 1024) acc[i] = 0;
  if (half == 0)
    for (int i = threadIdx.x; i < C_; i += 1024) cnt[i] = 0;
  __syncthreads();

  const int per = (N + NCHUNK - 1) / NCHUNK;
  const int a0 = chunk * per;
  const int aEnd = min(a0 + per, N);
  const int w = threadIdx.x >> 6;
  const int lane = threadIdx.x & 63;
  const int g = lane >> 4, t = lane & 15;
  const float4* h4 = (const float4*)h;

  int a = a0 + w * 4 + g;
  bool ok0 = a < aEnd, ok1 = (a + 64) < aEnd;
  float4 v0 = {}, v1 = {}; int c0 = 0, c1 = 0;
  if (ok0) { v0 = h4[(size_t)a * 32 + half * 16 + t]; c0 = (int)at[a]; }
  if (ok1) { v1 = h4[(size_t)(a + 64) * 32 + half * 16 + t]; c1 = (int)at[a + 64]; }

  while (ok0) {
    const int an = a + 128;
    const bool okn = an < aEnd;
    float4 vn = {}; int cn = 0;
    if (okn) { vn = h4[(size_t)an * 32 + half * 16 + t]; cn = (int)at[an]; }

    int* ap = &acc[c0 * 64 + t * 4];
    int iv0 = __float2int_rn(v0.x * SCALE);
    int iv1 = __float2int_rn(v0.y * SCALE);
    int iv2 = __float2int_rn(v0.z * SCALE);
    int iv3 = __float2int_rn(v0.w * SCALE);
    if (g == 0) { atomicAdd(&ap[0],iv0); atomicAdd(&ap[1],iv1); atomicAdd(&ap[2],iv2); atomicAdd(&ap[3],iv3); }
    else if (g == 1) { atomicAdd(&ap[1],iv1); atomicAdd(&ap[2],iv2); atomicAdd(&ap[3],iv3); atomicAdd(&ap[0],iv0); }
    else if (g == 2) { atomicAdd(&ap[2],iv2); atomicAdd(&ap[3],iv3); atomicAdd(&ap[0],iv0); atomicAdd(&ap[1],iv1); }
    else { atomicAdd(&ap[3],iv3); atomicAdd(&ap[0],iv0); atomicAdd(&ap[1],iv1); atomicAdd(&ap[2],iv2); }
    if (half == 0 && t == 0) atomicAdd(&cnt[c0], 1);

    a += 64;
    ok0 = ok1; v0 = v1; c0 = c1;
    ok1 = okn; v1 = vn; c1 = cn;
  }
  __syncthreads();

  if (dopart) {
    int* pb = psumI + (size_t)blockIdx.x * (C_ * 64);
    for (int i = threadIdx.x; i < C_ * 64; i += 1024) pb[i] = acc[i];
    if (half == 0) {
      int* pc = pcntI + (size_t)chunk * C_;
      for (int i = threadIdx.x; i < C_; i += 1024) pc[i] = cnt[i];
    }
  } else {
    for (int i = threadIdx.x; i < C_ * 64; i += 1024) {
      int vv = acc[i];
      if (vv != 0)
        atomicAdd(&sums[(size_t)(i >> 6) * D_ + half * 64 + (i & 63)],
                  (float)vv * INV_SCALE);
    }
    if (half == 0)
      for (int i = threadIdx.x; i < C_; i += 1024)
        if (cnt[i] != 0) atomicAdd(&countsF[i], (float)cnt[i]);
  }
}

// Kernel 3 (partials path): reduce s32 partials -> f32 sums, countsF.
__global__ __launch_bounds__(256) void k_reduce(
    const int* __restrict__ psumI, const int* __restrict__ pcntI,
    float* __restrict__ sums, float* __restrict__ countsF) {
  int idx = blockIdx.x * 256 + threadIdx.x;
  if (idx < C_ * D_) {
    int code = idx >> 7;
    int dim = idx & 127;
    int half = dim >> 6;
    int dl = dim & 63;
    const int* p = psumI + (size_t)half * (C_ * 64) + code * 64 + dl;
    float s = 0.f;
    for (int b = 0; b < NCHUNK; ++b)
      s += (float)p[(size_t)b * 2 * (C_ * 64)];
    sums[idx] = s * INV_SCALE;
  }
  if (idx < C_) {
    int s = 0;
    for (int b = 0; b < NCHUNK; ++b)
      s += pcntI[(size_t)b * C_ + idx];
    countsF[idx] = (float)s;
  }
}

// Kernel 4: EMA finalize + loss scalar.
__global__ __launch_bounds__(256) void k_final(
    const float* __restrict__ cb, const float* __restrict__ ecnt,
    const float* __restrict__ esum, const float* __restrict__ ws,
    float* __restrict__ out, int N) {
  const float* sums = ws;
  const float* countsF = ws + OFF_COUNTS;
  int idx = blockIdx.x * 256 + threadIdx.x;
  const size_t base = (size_t)N * D_ + N + 1;
  if (idx < C_ * D_) {
    int c = idx >> 7;
    int e4 = (c >> 2) << 2;
    bool present = (countsF[e4] + countsF[e4 + 1] + countsF[e4 + 2] + countsF[e4 + 3]) > 0.f;
    float es = esum[idx];
    float s  = sums[idx];
    float ns = present ? 0.99f * es + 0.01f * s : es;
    float ec = ecnt[c];
    float nc = present ? 0.99f * ec + 0.01f * countsF[c] : ec;
    float ncbv = present ? ns / fmaxf(nc, 1e-5f) : cb[idx];
    out[base + idx] = ncbv;
    if ((idx & 127) == 0) out[base + C_ * D_ + c] = nc;
    out[base + C_ * D_ + C_ + idx] = ns;
  }
  if (idx == 0) {
    float loss = ws[OFF_LOSS];
    out[(size_t)N * D_ + N] = 0.25f * loss / ((float)N * (float)D_);
  }
}

extern "C" void kernel_launch(void* const* d_in, const int* in_sizes, int n_in,
                              void* d_out, int out_size, void* d_ws, size_t ws_size,
                              hipStream_t stream) {
  // Identify inputs by size (robust to input-order changes).
  const float* h = nullptr; const int* ei = nullptr;
  const float* cb = nullptr; const float* ecnt = nullptr; const float* esum = nullptr;
  long hsz = -1; int hidx = -1;
  for (int i = 0; i < n_in; ++i)
    if ((long)in_sizes[i] > hsz) { hsz = in_sizes[i]; hidx = i; }
  h = (const float*)d_in[hidx];
  const int N = (int)(hsz / D_);
  for (int i = 0; i < n_in; ++i) {
    if (i == hidx) continue;
    const int s = in_sizes[i];
    if (s == N) ei = (const int*)d_in[i];
    else if (s == C_) ecnt = (const float*)d_in[i];
    else if (s == C_ * D_) { if (!cb) cb = (const float*)d_in[i]; else esum = (const float*)d_in[i]; }
  }

  float* out = (float*)d_out;
  float* hq  = out;
  float* at  = out + (size_t)N * D_;

  float* ws = (float*)d_ws;
  float* sums    = ws;
  float* countsF = ws + OFF_COUNTS;
  float* lossp   = ws + OFF_LOSS;
  int*   psumI   = (int*)(ws + OFF_PSUM);
  int*   pcntI   = (int*)(ws + OFF_PCNT);

  const int dopart = (ws_size >= WS_NEED_PART) ? 1 : 0;

  // zero sums/countsF/loss; psum partials fully overwritten
  hipMemsetAsync(d_ws, 0, (size_t)(OFF_LOSS + 1) * 4, stream);

  k_assign32<<<2048, 256, 0, stream>>>(h, ei, cb, hq, at, lossp, N);
  k_sums3<<<NCHUNK * 2, 1024, 0, stream>>>(h, at, psumI, pcntI,
                                           sums, countsF, dopart, N);
  if (dopart)
    k_reduce<<<(C_ * D_ + 255) / 256, 256, 0, stream>>>(psumI, pcntI, sums, countsF);
  k_final<<<(C_ * D_ + 255) / 256, 256, 0, stream>>>(cb, ecnt, esum, ws, out, N);
}